// Round 5
// baseline (295.185 us; speedup 1.0000x reference)
//
#include <hip/hip_runtime.h>

typedef __bf16 bf16x8 __attribute__((ext_vector_type(8)));
typedef float f32x4 __attribute__((ext_vector_type(4)));
typedef __attribute__((address_space(1))) const unsigned char ga_t;
typedef __attribute__((address_space(3))) unsigned char la_t;

static __device__ __forceinline__ unsigned short f2b(float f) {
  union { float f; unsigned int i; } c; c.f = f;
  unsigned int r = c.i + 0x7FFFu + ((c.i >> 16) & 1u);
  return (unsigned short)(r >> 16);
}
static __device__ __forceinline__ unsigned int pack2(float a, float b) {
  return (unsigned int)f2b(a) | ((unsigned int)f2b(b) << 16);
}
static __device__ __forceinline__ int4 ld8f_cvt(const float* __restrict__ p) {
  float4 a = *(const float4*)p;
  float4 b = *(const float4*)(p + 4);
  unsigned short u[8];
  u[0] = f2b(a.x); u[1] = f2b(a.y); u[2] = f2b(a.z); u[3] = f2b(a.w);
  u[4] = f2b(b.x); u[5] = f2b(b.y); u[6] = f2b(b.z); u[7] = f2b(b.w);
  return *(int4*)u;
}
static __device__ __forceinline__ void glds16(const unsigned short* g, unsigned short* l) {
  __builtin_amdgcn_global_load_lds((ga_t*)g, (la_t*)l, 16, 0, 0);
}

// fp32 -> bf16 convert, up to 4 streams via blockIdx.y
__global__ __launch_bounds__(256)
void cvt_z(const float* __restrict__ s0, const float* __restrict__ s1,
           const float* __restrict__ s2, const float* __restrict__ s3,
           unsigned short* d0, unsigned short* d1,
           unsigned short* d2, unsigned short* d3, int n8) {
  const int z = blockIdx.y;
  const float* s = z == 0 ? s0 : z == 1 ? s1 : z == 2 ? s2 : s3;
  unsigned short* d = z == 0 ? d0 : z == 1 ? d1 : z == 2 ? d2 : d3;
  int idx = blockIdx.x * 256 + threadIdx.x;
  if (idx < n8) *(int4*)(d + (size_t)idx * 8) = ld8f_cvt(s + (size_t)idx * 8);
}

// ---------------------------------------------------------------------------
// Shared GEMM core: 128x128 tile, BK=32, global_load_lds width-16 staging
// into UNPADDED 128x32 LDS tiles (lane-linear; glds requires it).
// ---------------------------------------------------------------------------
static __device__ __forceinline__ void gemm_core(
    const unsigned short* __restrict__ A, const unsigned short* __restrict__ W,
    unsigned short* sA, unsigned short* sB, f32x4 acc[4][4],
    int K, int m0, int n0) {
  const int tid = threadIdx.x;
  const int wave = tid >> 6, lane = tid & 63, quad = lane >> 4, l16 = lane & 15;
  const int wrow = (wave >> 1) * 64, wcol = (wave & 1) * 64;
  const int r = tid >> 2, c8 = (tid & 3) * 8;

  const unsigned short* gA0 = A + (size_t)(m0 + r) * K + c8;
  const unsigned short* gA1 = gA0 + (size_t)64 * K;
  const unsigned short* gB0 = W + (size_t)(n0 + r) * K + c8;
  const unsigned short* gB1 = gB0 + (size_t)64 * K;
  unsigned short* lA0 = sA + tid * 8;
  unsigned short* lA1 = lA0 + 2048;
  unsigned short* lB0 = sB + tid * 8;
  unsigned short* lB1 = lB0 + 2048;

  for (int k0 = 0; k0 < K; k0 += 32) {
    __syncthreads();
    glds16(gA0 + k0, lA0);
    glds16(gA1 + k0, lA1);
    glds16(gB0 + k0, lB0);
    glds16(gB1 + k0, lB1);
    __syncthreads();

    bf16x8 af[4], bfv[4];
#pragma unroll
    for (int i = 0; i < 4; ++i)
      af[i] = *(const bf16x8*)(&sA[(wrow + i * 16 + l16) * 32 + quad * 8]);
#pragma unroll
    for (int j = 0; j < 4; ++j)
      bfv[j] = *(const bf16x8*)(&sB[(wcol + j * 16 + l16) * 32 + quad * 8]);
#pragma unroll
    for (int i = 0; i < 4; ++i)
#pragma unroll
      for (int j = 0; j < 4; ++j)
        acc[i][j] = __builtin_amdgcn_mfma_f32_16x16x32_bf16(af[i], bfv[j], acc[i][j], 0, 0, 0);
  }
}

// QKV fused GEMM: z selects projection. z<2 -> bf16 C row-major;
// z==2 -> bf16 C^T (V transposed for attention), via per-wave LDS transpose.
__global__ __launch_bounds__(256, 3)
void gemm_qkv(const unsigned short* __restrict__ A0p, const unsigned short* __restrict__ A1p,
              const unsigned short* __restrict__ A2p,
              const unsigned short* __restrict__ W0p, const unsigned short* __restrict__ W1p,
              const unsigned short* __restrict__ W2p,
              const float* __restrict__ b0p, const float* __restrict__ b1p,
              const float* __restrict__ b2p,
              unsigned short* __restrict__ C0p, unsigned short* __restrict__ C1p,
              unsigned short* __restrict__ C2p,
              int M, int N, int K, int zbase) {
  __shared__ __align__(16) unsigned short smem[8192];  // sA | sB, 16 KB
  const int z = blockIdx.z + zbase;
  const unsigned short* A = z == 0 ? A0p : z == 1 ? A1p : A2p;
  const unsigned short* W = z == 0 ? W0p : z == 1 ? W1p : W2p;
  const float* bias = z == 0 ? b0p : z == 1 ? b1p : b2p;

  const int tid = threadIdx.x;
  const int wave = tid >> 6, lane = tid & 63, quad = lane >> 4, l16 = lane & 15;
  const int m0 = blockIdx.x * 128, n0 = blockIdx.y * 128;
  const int wrow = (wave >> 1) * 64, wcol = (wave & 1) * 64;

  f32x4 acc[4][4];
#pragma unroll
  for (int i = 0; i < 4; ++i)
#pragma unroll
    for (int j = 0; j < 4; ++j) acc[i][j] = (f32x4){0.f, 0.f, 0.f, 0.f};

  gemm_core(A, W, smem, smem + 4096, acc, K, m0, n0);

  if (z < 2) {
    unsigned short* C = z == 0 ? C0p : C1p;
#pragma unroll
    for (int j = 0; j < 4; ++j) {
      const int col = n0 + wcol + j * 16 + l16;
      const float bv = bias[col];
#pragma unroll
      for (int i = 0; i < 4; ++i)
#pragma unroll
        for (int r = 0; r < 4; ++r) {
          const int row = m0 + wrow + i * 16 + quad * 4 + r;
          C[(size_t)row * N + col] = f2b(acc[i][j][r] + bv);
        }
    }
  } else {
    // transpose epilogue: reuse smem (per-wave 16x72 chunk), 4 passes of 16 cols
    __syncthreads();  // all waves done with frag reads before clobbering smem
    unsigned short* sT = smem + wave * 1152;
#pragma unroll
    for (int j = 0; j < 4; ++j) {
      const float bv = bias[n0 + wcol + j * 16 + l16];
#pragma unroll
      for (int i = 0; i < 4; ++i) {
        uint2 pk;
        pk.x = pack2(acc[i][j][0] + bv, acc[i][j][1] + bv);
        pk.y = pack2(acc[i][j][2] + bv, acc[i][j][3] + bv);
        *(uint2*)(&sT[l16 * 72 + i * 16 + quad * 4]) = pk;
      }
      // same-wave LDS write->read (DS in-order within a wave)
#pragma unroll
      for (int t = 0; t < 2; ++t) {
        const int nl = lane >> 2;
        const int colh = (lane & 3) * 8 + t * 32;
        int4 v = *(const int4*)(&sT[nl * 72 + colh]);
        *(int4*)(&C2p[(size_t)(n0 + wcol + j * 16 + nl) * M + m0 + wrow + colh]) = v;
      }
    }
  }
}

// Output GEMM: bf16 A (attn out), bf16 W, fp32 C = d_out
__global__ __launch_bounds__(256, 3)
void gemm_out(const unsigned short* __restrict__ A, const unsigned short* __restrict__ W,
              const float* __restrict__ bias, float* __restrict__ C,
              int M, int N, int K) {
  __shared__ __align__(16) unsigned short smem[8192];
  const int tid = threadIdx.x;
  const int wave = tid >> 6, lane = tid & 63, quad = lane >> 4, l16 = lane & 15;
  const int m0 = blockIdx.x * 128, n0 = blockIdx.y * 128;
  const int wrow = (wave >> 1) * 64, wcol = (wave & 1) * 64;

  f32x4 acc[4][4];
#pragma unroll
  for (int i = 0; i < 4; ++i)
#pragma unroll
    for (int j = 0; j < 4; ++j) acc[i][j] = (f32x4){0.f, 0.f, 0.f, 0.f};

  gemm_core(A, W, smem, smem + 4096, acc, K, m0, n0);

#pragma unroll
  for (int j = 0; j < 4; ++j) {
    const int col = n0 + wcol + j * 16 + l16;
    const float bv = bias[col];
#pragma unroll
    for (int i = 0; i < 4; ++i)
#pragma unroll
      for (int r = 0; r < 4; ++r) {
        const int row = m0 + wrow + i * 16 + quad * 4 + r;
        C[(size_t)row * N + col] = acc[i][j][r] + bv;
      }
  }
}

// ---------------------------------------------------------------------------
// Fused attention v4: 2-wave blocks, 64 q rows/wave (128 q/block), Q frags
// straight from global, register-prefetched K/V staging, S^T MFMA order,
// sP stride 88 (b64 writes <=2-way, b128 reads conflict-free). 40 KB LDS ->
// 4 blocks/CU.
// ---------------------------------------------------------------------------
#define SEQ 2048
#define DMODEL 1024

__global__ __launch_bounds__(128, 2)
void attn_fused(const unsigned short* __restrict__ Q,
                const unsigned short* __restrict__ Km,
                const unsigned short* __restrict__ Vt,   // [1024][4096]
                unsigned short* __restrict__ O) {
  __shared__ __align__(16) unsigned short sK[64 * 72];
  __shared__ __align__(16) unsigned short sVt[64 * 72];
  __shared__ __align__(16) unsigned short sP[2][64 * 88];

  const int tid = threadIdx.x;
  const int wave = tid >> 6, lane = tid & 63, quad = lane >> 4, l16 = lane & 15;
  const int qt = blockIdx.x;        // 0..15
  const int bh = blockIdx.y;        // 0..31
  const int b = bh >> 4, h = bh & 15;
  const size_t qrow0 = (size_t)b * SEQ + qt * 128 + wave * 64;
  const size_t kvrow0 = (size_t)b * SEQ;
  const int hcol = h * 64;
  const int bofs = b * SEQ;

  // Q fragments straight from global (once): 8 int4 gathers
  bf16x8 qa[4][2];
#pragma unroll
  for (int qg = 0; qg < 4; ++qg)
#pragma unroll
    for (int ks = 0; ks < 2; ++ks) {
      int4 v = *(const int4*)(&Q[(qrow0 + qg * 16 + l16) * DMODEL + hcol + ks * 32 + quad * 8]);
      qa[qg][ks] = *(bf16x8*)&v;
    }

  f32x4 acc[4][4];
#pragma unroll
  for (int qg = 0; qg < 4; ++qg)
#pragma unroll
    for (int hg = 0; hg < 4; ++hg) acc[qg][hg] = (f32x4){0.f, 0.f, 0.f, 0.f};
  float lsum[4] = {0.f, 0.f, 0.f, 0.f};

  const float SCL = 0.18033688011112042f;  // log2(e)/sqrt(64)

  // staging geometry: idx = tid + i*128 -> row idx>>3 (0..63), col (idx&7)*8
  const int srow = tid >> 3, scol = (tid & 7) * 8;

  // preload tile 0
  int4 kpre[4], vpre[4];
#pragma unroll
  for (int i = 0; i < 4; ++i) {
    const int rr = srow + i * 16;
    kpre[i] = *(const int4*)(&Km[(kvrow0 + rr) * DMODEL + hcol + scol]);
    vpre[i] = *(const int4*)(&Vt[(size_t)(hcol + rr) * 4096 + bofs + scol]);
  }

  for (int kt = 0; kt < SEQ; kt += 64) {
    __syncthreads();
#pragma unroll
    for (int i = 0; i < 4; ++i) {
      const int rr = srow + i * 16;
      *(int4*)(&sK[rr * 72 + scol]) = kpre[i];
      *(int4*)(&sVt[rr * 72 + scol]) = vpre[i];
    }
    __syncthreads();

    // prefetch next tile (issues now, waited on at next iteration's writes)
    const int ktn = (kt + 64 < SEQ) ? kt + 64 : kt;
#pragma unroll
    for (int i = 0; i < 4; ++i) {
      const int rr = srow + i * 16;
      kpre[i] = *(const int4*)(&Km[(kvrow0 + ktn + rr) * DMODEL + hcol + scol]);
      vpre[i] = *(const int4*)(&Vt[(size_t)(hcol + rr) * 4096 + bofs + ktn + scol]);
    }

#pragma unroll
    for (int kh = 0; kh < 2; ++kh) {     // two 32-key halves
      // S^T = K Q^T for this half: D[key][q]
      f32x4 s[4][2];
#pragma unroll
      for (int qg = 0; qg < 4; ++qg)
#pragma unroll
        for (int kg = 0; kg < 2; ++kg) s[qg][kg] = (f32x4){0.f, 0.f, 0.f, 0.f};
#pragma unroll
      for (int kg = 0; kg < 2; ++kg) {
        const int key16 = kh * 2 + kg;
        bf16x8 kb0 = *(const bf16x8*)(&sK[(key16 * 16 + l16) * 72 + quad * 8]);
        bf16x8 kb1 = *(const bf16x8*)(&sK[(key16 * 16 + l16) * 72 + 32 + quad * 8]);
#pragma unroll
        for (int qg = 0; qg < 4; ++qg) {
          s[qg][kg] = __builtin_amdgcn_mfma_f32_16x16x32_bf16(kb0, qa[qg][0], s[qg][kg], 0, 0, 0);
          s[qg][kg] = __builtin_amdgcn_mfma_f32_16x16x32_bf16(kb1, qa[qg][1], s[qg][kg], 0, 0, 0);
        }
      }
      // exp, partial row sums, packed b64 P-writes (q-major, stride 88)
#pragma unroll
      for (int qg = 0; qg < 4; ++qg)
#pragma unroll
        for (int kg = 0; kg < 2; ++kg) {
          float p0 = __builtin_amdgcn_exp2f(s[qg][kg][0] * SCL);
          float p1 = __builtin_amdgcn_exp2f(s[qg][kg][1] * SCL);
          float p2 = __builtin_amdgcn_exp2f(s[qg][kg][2] * SCL);
          float p3 = __builtin_amdgcn_exp2f(s[qg][kg][3] * SCL);
          lsum[qg] += (p0 + p1) + (p2 + p3);
          uint2 pk; pk.x = pack2(p0, p1); pk.y = pack2(p2, p3);
          *(uint2*)(&sP[wave][(qg * 16 + l16) * 88 + (kh * 2 + kg) * 16 + quad * 4]) = pk;
        }
      // O += P V for this 32-key half (same-wave LDS, in-order)
      bf16x8 paf[4], vbf[4];
#pragma unroll
      for (int qg = 0; qg < 4; ++qg)
        paf[qg] = *(const bf16x8*)(&sP[wave][(qg * 16 + l16) * 88 + kh * 32 + quad * 8]);
#pragma unroll
      for (int hg = 0; hg < 4; ++hg)
        vbf[hg] = *(const bf16x8*)(&sVt[(hg * 16 + l16) * 72 + kh * 32 + quad * 8]);
#pragma unroll
      for (int qg = 0; qg < 4; ++qg)
#pragma unroll
        for (int hg = 0; hg < 4; ++hg)
          acc[qg][hg] = __builtin_amdgcn_mfma_f32_16x16x32_bf16(paf[qg], vbf[hg], acc[qg][hg], 0, 0, 0);
    }
  }

  // row sums: lane holds partial for q=qg*16+l16 over its quad's keys
  float linv[4][4];
#pragma unroll
  for (int qg = 0; qg < 4; ++qg) {
    float v = lsum[qg];
    v += __shfl_xor(v, 16, 64);
    v += __shfl_xor(v, 32, 64);
    lsum[qg] = v;
  }
#pragma unroll
  for (int qg = 0; qg < 4; ++qg)
#pragma unroll
    for (int r = 0; r < 4; ++r)
      linv[qg][r] = 1.0f / __shfl(lsum[qg], quad * 4 + r, 64);

#pragma unroll
  for (int qg = 0; qg < 4; ++qg)
#pragma unroll
    for (int hg = 0; hg < 4; ++hg)
#pragma unroll
      for (int r = 0; r < 4; ++r) {
        const size_t row = qrow0 + qg * 16 + quad * 4 + r;
        O[row * DMODEL + hcol + hg * 16 + l16] = f2b(acc[qg][hg][r] * linv[qg][r]);
      }
}

// ---------------------------------------------------------------------------
extern "C" void kernel_launch(void* const* d_in, const int* in_sizes, int n_in,
                              void* d_out, int out_size, void* d_ws, size_t ws_size,
                              hipStream_t stream) {
  const float* xq = (const float*)d_in[0];
  const float* xv = (const float*)d_in[1];
  const float* xk = (const float*)d_in[2];
  const float* Wq = (const float*)d_in[3];
  const float* bq = (const float*)d_in[4];
  const float* Wk = (const float*)d_in[5];
  const float* bk = (const float*)d_in[6];
  const float* Wv = (const float*)d_in[7];
  const float* bv = (const float*)d_in[8];
  const float* Wo = (const float*)d_in[9];
  const float* bo = (const float*)d_in[10];
  float* out = (float*)d_out;

  const int S = 2048, D = 1024, M = 4096;
  const size_t MD = (size_t)M * D, DD = (size_t)D * D;
  unsigned short* P = (unsigned short*)d_ws;
  dim3 bb(256);
  dim3 gg(M / 128, D / 128);

  const size_t need = (3 * MD + 4 * DD + 3 * MD) * 2;
  if (ws_size >= need) {
    // fused path: all QKV in one z=3 launch (768 blocks = 3/CU)
    unsigned short* Ab = P;            // 3 act slices
    unsigned short* Wb = Ab + 3 * MD;  // 4 weight slices (q,k,v,o)
    unsigned short* Qw = Wb + 4 * DD;
    unsigned short* Kw = Qw + MD;
    unsigned short* Vtw = Kw + MD;
    unsigned short* Ao = Ab;           // attn out reuses act slice 0

    cvt_z<<<dim3((int)(MD / 8 / 256), 3), bb, 0, stream>>>(
        xq, xk, xv, xq, Ab, Ab + MD, Ab + 2 * MD, Ab, (int)(MD / 8));
    cvt_z<<<dim3((int)(DD / 8 / 256), 4), bb, 0, stream>>>(
        Wq, Wk, Wv, Wo, Wb, Wb + DD, Wb + 2 * DD, Wb + 3 * DD, (int)(DD / 8));
    gemm_qkv<<<dim3(M / 128, D / 128, 3), bb, 0, stream>>>(
        Ab, Ab + MD, Ab + 2 * MD, Wb, Wb + DD, Wb + 2 * DD,
        bq, bk, bv, Qw, Kw, Vtw, M, D, D, 0);
    attn_fused<<<dim3(S / 128, 32), dim3(128), 0, stream>>>(Qw, Kw, Vtw, Ao);
    gemm_out<<<gg, bb, 0, stream>>>(Ao, Wb + 3 * DD, bo, out, M, D, D);
  } else {
    // sequential fallback (34 MB): act 8MB | W 2MB | Q 8 | K 8 | Vt 8
    unsigned short* Ab = P;
    unsigned short* Wb = Ab + MD;
    unsigned short* Qw = Wb + DD;
    unsigned short* Kw = Qw + MD;
    unsigned short* Vtw = Kw + MD;
    unsigned short* Ao = Ab;
    const int an = (int)(MD / 8), wn = (int)(DD / 8);

    cvt_z<<<dim3(an / 256, 1), bb, 0, stream>>>(xq, xq, xq, xq, Ab, Ab, Ab, Ab, an);
    cvt_z<<<dim3(wn / 256, 1), bb, 0, stream>>>(Wq, Wq, Wq, Wq, Wb, Wb, Wb, Wb, wn);
    gemm_qkv<<<dim3(M / 128, D / 128, 1), bb, 0, stream>>>(
        Ab, Ab, Ab, Wb, Wb, Wb, bq, bq, bq, Qw, Qw, Qw, M, D, D, 0);

    cvt_z<<<dim3(an / 256, 1), bb, 0, stream>>>(xk, xk, xk, xk, Ab, Ab, Ab, Ab, an);
    cvt_z<<<dim3(wn / 256, 1), bb, 0, stream>>>(Wk, Wk, Wk, Wk, Wb, Wb, Wb, Wb, wn);
    gemm_qkv<<<dim3(M / 128, D / 128, 1), bb, 0, stream>>>(
        Ab, Ab, Ab, Wb, Wb, Wb, bk, bk, bk, Kw, Kw, Kw, M, D, D, 0);

    cvt_z<<<dim3(an / 256, 1), bb, 0, stream>>>(xv, xv, xv, xv, Ab, Ab, Ab, Ab, an);
    cvt_z<<<dim3(wn / 256, 1), bb, 0, stream>>>(Wv, Wv, Wv, Wv, Wb, Wb, Wb, Wb, wn);
    gemm_qkv<<<dim3(M / 128, D / 128, 1), bb, 0, stream>>>(
        Ab, Ab, Ab, Wb, Wb, Wb, bv, bv, bv, Vtw, Vtw, Vtw, M, D, D, 2);

    attn_fused<<<dim3(S / 128, 32), dim3(128), 0, stream>>>(Qw, Kw, Vtw, Ao);

    cvt_z<<<dim3(wn / 256, 1), bb, 0, stream>>>(Wo, Wo, Wo, Wo, Wb, Wb, Wb, Wb, wn);
    gemm_out<<<gg, bb, 0, stream>>>(Ao, Wb, bo, out, M, D, D);
  }
}